// Round 3
// baseline (397.006 us; speedup 1.0000x reference)
//
#include <hip/hip_runtime.h>

#define B_SZ 2
#define E_SZ 1024
#define C_SZ 128
#define R_REL 32
#define TS 64
#define TO 64

typedef float f32x4 __attribute__((ext_vector_type(4)));

// 8 MiB static G buffer: no workspace dependency, no fallback ambiguity.
__device__ float g_G[(size_t)B_SZ * E_SZ * E_SZ];

// ---------------------------------------------------------------------------
// K1: Gram tiles. G[b,s,o] = sum_c x[b,s,c] * x[b,o,c]
// Verified numerics (same staging + accumulation order as round-0 kernel).
// 512 blocks, ~12 us.
// ---------------------------------------------------------------------------
__global__ __launch_bounds__(256, 2) void gram_tile(
        const float* __restrict__ x) {
    __shared__ float xs[TS][C_SZ + 4];
    __shared__ float xo[TO][C_SZ + 4];

    const int b  = blockIdx.z;
    const int s0 = blockIdx.y * TS;
    const int o0 = blockIdx.x * TO;
    const int tid = threadIdx.x;

    const float4* src_s = (const float4*)(x + (size_t)b * E_SZ * C_SZ + (size_t)s0 * C_SZ);
    const float4* src_o = (const float4*)(x + (size_t)b * E_SZ * C_SZ + (size_t)o0 * C_SZ);
    #pragma unroll
    for (int i = tid; i < TS * (C_SZ / 4); i += 256) {
        const int row = i >> 5;
        const int col = (i & 31) << 2;
        *(float4*)&xs[row][col] = src_s[i];
        *(float4*)&xo[row][col] = src_o[i];
    }
    __syncthreads();

    const int tx = tid & 15;
    const int ty = tid >> 4;
    const int si = ty << 2;
    const int oj = tx << 2;

    float acc[4][4];
    #pragma unroll
    for (int ii = 0; ii < 4; ++ii)
        #pragma unroll
        for (int jj = 0; jj < 4; ++jj) acc[ii][jj] = 0.f;

    #pragma unroll 4
    for (int c = 0; c < C_SZ; c += 4) {
        float4 a[4], bb[4];
        #pragma unroll
        for (int ii = 0; ii < 4; ++ii) a[ii]  = *(const float4*)&xs[si + ii][c];
        #pragma unroll
        for (int jj = 0; jj < 4; ++jj) bb[jj] = *(const float4*)&xo[oj + jj][c];
        #pragma unroll
        for (int ii = 0; ii < 4; ++ii) {
            #pragma unroll
            for (int jj = 0; jj < 4; ++jj) {
                acc[ii][jj] += a[ii].x * bb[jj].x + a[ii].y * bb[jj].y
                             + a[ii].z * bb[jj].z + a[ii].w * bb[jj].w;
            }
        }
    }

    #pragma unroll
    for (int ii = 0; ii < 4; ++ii) {
        float4 gv;
        gv.x = acc[ii][0]; gv.y = acc[ii][1]; gv.z = acc[ii][2]; gv.w = acc[ii][3];
        *(float4*)(g_G + ((size_t)b * E_SZ + (size_t)(s0 + si + ii)) * E_SZ + o0 + oj) = gv;
    }
}

// ---------------------------------------------------------------------------
// K2: pure stream. out[b,s,r,o] = G[b,s,o] * R[r,s,o]
// One block per s (1024 blocks = 4/CU). Thread t owns float4 column t for
// BOTH batches -> each R element fetched exactly once from HBM.
//
// Round-3 fix: __launch_bounds__(256, 4). The previous (256, 8) capped the
// allocator at ~64 VGPRs; the unrolled body (in-flight loads + scaled store
// temps + 64-bit addressing) needs ~70+, so the compiler serialized/spilled
// and memory-level parallelism collapsed (~2.5 TB/s). At 4 waves/EU we get
// <=128 VGPRs: unroll 8 keeps 8 independent HBM loads in flight per wave;
// 16 waves/CU x 8 x 1KB is far more than the ~10 KB/CU needed to cover
// ~900-cycle HBM latency.
// ---------------------------------------------------------------------------
__global__ __launch_bounds__(256, 4) void scale_stream(
        const float* __restrict__ R,
        float* __restrict__ out) {
    const int o4 = threadIdx.x;            // float4 column 0..255
    const int s  = blockIdx.x;             // 0..1023

    const f32x4* G4 = (const f32x4*)g_G;
    const f32x4* R4 = (const f32x4*)R;
    f32x4*       O4 = (f32x4*)out;

    const f32x4 g0 = G4[(size_t)s * (E_SZ / 4) + o4];
    const f32x4 g1 = G4[(size_t)(E_SZ + s) * (E_SZ / 4) + o4];

    const f32x4* rp  = R4 + (size_t)s * (E_SZ / 4) + o4;                    // R[0,s,o4]
    f32x4*       op0 = O4 + (size_t)s * (R_REL * E_SZ / 4) + o4;            // out[0,s,0,o4]
    f32x4*       op1 = O4 + (size_t)(E_SZ + s) * (R_REL * E_SZ / 4) + o4;   // out[1,s,0,o4]

    #pragma unroll 8
    for (int r = 0; r < R_REL; ++r) {
        const f32x4 rv = rp[(size_t)r * (E_SZ * E_SZ / 4)];  // stride 4 MiB
        op0[r * (E_SZ / 4)] = rv * g0;                       // stride 4 KiB
        op1[r * (E_SZ / 4)] = rv * g1;
    }
}

extern "C" void kernel_launch(void* const* d_in, const int* in_sizes, int n_in,
                              void* d_out, int out_size, void* d_ws, size_t ws_size,
                              hipStream_t stream) {
    const float* x = (const float*)d_in[0];
    const float* R = (const float*)d_in[1];
    float* out = (float*)d_out;

    dim3 g1(E_SZ / TO, E_SZ / TS, B_SZ);   // 512 blocks
    gram_tile<<<g1, 256, 0, stream>>>(x);
    scale_stream<<<dim3(E_SZ), 256, 0, stream>>>(R, out);  // 1024 blocks
}